// Round 22
// baseline (5415.519 us; speedup 1.0000x reference)
//
#include <hip/hip_runtime.h>

#define B_TOT 1024
#define L_T   100
#define DIN   32
#define HID   128
#define DOUT  32
#define BT    32      // batch rows per block
#define NHG   8       // h-groups (fwf split 8 ways -> 128 KiB LDS slice)
#define NBLK  256     // 32 batch-tiles x 8 h-groups = 256 CUs, 1 block/CU
#define NTHREADS 1024 // 16 waves

typedef _Float16 half8 __attribute__((ext_vector_type(8)));
typedef float    f32x4 __attribute__((ext_vector_type(4)));

// XOR-swizzled index into a [rows][128] f16 LDS tile (conflict-free b128 reads)
#define SWZ(r,c) (((r) << 7) + ((c) ^ (((r) & 7) << 3)))

__device__ __forceinline__ float fast_exp2(float x){
#if __has_builtin(__builtin_amdgcn_exp2f)
  return __builtin_amdgcn_exp2f(x);
#else
  float r; asm("v_exp_f32 %0, %1\n\ts_nop 1" : "=v"(r) : "v"(x)); return r;
#endif
}
__device__ __forceinline__ float fast_rcp(float x){
#if __has_builtin(__builtin_amdgcn_rcpf)
  return __builtin_amdgcn_rcpf(x);
#else
  float r; asm("v_rcp_f32 %0, %1\n\ts_nop 1" : "=v"(r) : "v"(x)); return r;
#endif
}
__device__ __forceinline__ float fast_tanh(float x){
  float e = fast_exp2(x * 2.885390081777926f);  // 2*log2(e)
  return 1.0f - 2.0f * fast_rcp(e + 1.0f);
}

// Reorder [N][K] f32 row-major weights into fragment-ready f16 tiles:
// dst[((tile*(K/32)+k0)*64 + lane)*8 + ki], lane = (n&15) + 16*((k>>3)&3)
__global__ void reorder_w(const float* __restrict__ src, _Float16* __restrict__ dst,
                          int N, int K){
  int id = blockIdx.x * 256 + threadIdx.x;
  if (id >= N * K) return;
  int n = id / K, k = id - n * K;
  int tile = n >> 4, nl = n & 15;
  int kq = (k >> 3) & 3, k0 = k >> 5, ki = k & 7;
  int lane = nl + (kq << 4);
  int K32 = K >> 5;
  dst[(((tile * K32 + k0) << 6) + lane) * 8 + ki] = (_Float16)src[id];
}

// r21 winner (3037 us; XCD-local groups, fence-free coherent exchange) with
// the rendezvous de-barriered: (1) per-wave flag adds — each producer wave
// (0..7, the dz-storing waves) drains its OWN vmcnt(0) then lane-0 adds 1;
// flag target = 64*epoch (8 waves x 8 blocks). No pre-flag block barrier.
// (2) all-wave spin — every wave polls the flag itself (uniform branch,
// one coalesced load/wave/poll from the LOCAL L2) and proceeds on
// observation. No post-spin broadcast barrier. Saves ~2 barriers/stage.
__global__ __launch_bounds__(NTHREADS) void cde_main(
    const float* __restrict__ coeffs, const float* __restrict__ times,
    const float* __restrict__ init_b, const float* __restrict__ fb0,
    const float* __restrict__ fb1,    const float* __restrict__ fb2,
    const float* __restrict__ fbf,    const float* __restrict__ dec_b,
    const _Float16* __restrict__ W,   float* __restrict__ dzg,
    unsigned int* __restrict__ flags, float* __restrict__ out)
{
  __shared__ _Float16 wslice[32*2048]; // 128 KiB: this block's fwf tiles (resident)
  __shared__ _Float16 bufA[BT*HID];    // 8 KiB ping-pong activations (f16, swizzled)
  __shared__ _Float16 bufB[BT*HID];    // 8 KiB
  __shared__ float    dzs[BT][16];     // 2 KiB  dz slice staging
  __shared__ float    dxs[BT][DIN];    // 4 KiB  dX/dt
  __shared__ float    fbfs[512];       // 2 KiB  fbf slice
  // total 155,648 B < 160 KiB

  const int tid  = threadIdx.x;
  const int lane = tid & 63;
  const int w    = tid >> 6;   // wave 0..15
  const int cl   = lane & 15;
  const int g    = lane >> 4;
  const int hg   = blockIdx.x >> 5;  // h-group (XCD-local grouping)
  const int bt   = blockIdx.x & 31;  // batch tile; group = {bt+32*hg} all same XCD
  const int b0   = bt * BT;
  const int cr   = tid >> 5;         // combine row 0..31
  const int cc   = (tid & 31) * 4;   // combine col base

  const _Float16* W0 = W;
  const _Float16* W1 = W + 16384;
  const _Float16* W2 = W + 32768;
  const _Float16* Wf = W + 49152;   // fwf: 256 tiles
  const _Float16* Wi = W + 573440;  // init_w
  const _Float16* Wd = W + 577536;  // dec_w
  const _Float16* Wfs = Wf + hg * 32 * 2048;  // this block's 32 tiles
  unsigned int* flag = flags + bt * 32;       // 128B-strided counter per group

  // lgkm-only local barrier (two-sided clobbers + sched pins).
  auto bar = [&]{
    __builtin_amdgcn_sched_barrier(0);
    asm volatile("s_waitcnt lgkmcnt(0)" ::: "memory");
    __builtin_amdgcn_s_barrier();
    __builtin_amdgcn_sched_barrier(0);
    asm volatile("" ::: "memory");
  };

  // fbf slice (global idx = 512*hg + t_local*16 + nl)
  if (tid < 512) fbfs[tid] = fbf[hg*512 + tid];

  // ---- init: z0 = coeffs[:,0,:] @ init_w.T + init_b (wslice as f32 scratch)
  float* scratch = (float*)wslice;   // [32][128] f32, overwritten later
  {
    int r = tid >> 5, d = tid & 31;
    bufB[SWZ(r, d)] = (_Float16)coeffs[(b0 + r)*(L_T*DIN) + d];
  }
  bar();
  {
    const int rt = w >> 3, ct = w & 7;
    f32x4 acc = {0.f,0.f,0.f,0.f};
    half8 a = *(const half8*)(bufB + SWZ(rt*16 + cl, 8*g));
    half8 b = *(const half8*)(Wi + (ct*64 + lane)*8);
    acc = __builtin_amdgcn_mfma_f32_16x16x32_f16(a, b, acc, 0, 0, 0);
    float bn = init_b[ct*16 + cl];
#pragma unroll
    for (int r = 0; r < 4; ++r){
      float v = acc[r] + bn;
      scratch[(rt*16 + 4*g + r)*128 + ct*16 + cl] = v;
      bufA[SWZ(rt*16 + 4*g + r, ct*16 + cl)] = (_Float16)v;
    }
  }
  bar();
  float zf[4], ka[4] = {0.f,0.f,0.f,0.f};
#pragma unroll
  for (int j = 0; j < 4; ++j) zf[j] = scratch[cr*128 + cc + j];
  bar();
  // ---- fwf slice -> LDS (once; replaces scratch)
  for (int i = tid*8; i < 32*2048; i += NTHREADS*8)
    *(half8*)(wslice + i) = *(const half8*)(Wfs + i);
  bar();

// Dense HID->HID, all 16 waves (rt=w>>3, ct=w&7), weights from L2/L3.
#define DENSE(IN, OB, WT, BIAS) {                                          \
    const int rt = w >> 3, ct = w & 7;                                     \
    f32x4 acc = {0.f,0.f,0.f,0.f};                                         \
    _Pragma("unroll")                                                      \
    for (int kq = 0; kq < 4; ++kq){                                        \
      half8 a = *(const half8*)((IN) + SWZ(rt*16 + cl, kq*32 + 8*g));      \
      half8 b = *(const half8*)((WT) + ((ct*4 + kq)*64 + lane)*8);         \
      acc = __builtin_amdgcn_mfma_f32_16x16x32_f16(a, b, acc, 0,0,0);}     \
    float bn = (BIAS)[ct*16 + cl];                                         \
    _Pragma("unroll")                                                      \
    for (int r = 0; r < 4; ++r)                                            \
      (OB)[SWZ(rt*16 + 4*g + r, ct*16 + cl)] = (_Float16)fast_tanh(acc[r] + bn); }

// Decoder (hg==0 blocks, waves 0..3): rt=w>>1, ct=w&1
#define DECODER(TS) {                                                      \
    const int rt = w >> 1, ct = w & 1;                                     \
    f32x4 acc = {0.f,0.f,0.f,0.f};                                         \
    _Pragma("unroll")                                                      \
    for (int kq = 0; kq < 4; ++kq){                                        \
      half8 a = *(const half8*)(bufA + SWZ(rt*16 + cl, kq*32 + 8*g));      \
      half8 b = *(const half8*)(Wd + ((ct*4 + kq)*64 + lane)*8);           \
      acc = __builtin_amdgcn_mfma_f32_16x16x32_f16(a, b, acc, 0,0,0);}     \
    float bn = dec_b[ct*16 + cl];                                          \
    _Pragma("unroll")                                                      \
    for (int r = 0; r < 4; ++r)                                            \
      out[(b0 + rt*16 + 4*g + r)*(L_T*DOUT) + (TS)*DOUT + ct*16 + cl] = acc[r] + bn; }

  const int rt_b = w & 1, hp = w >> 1;   // biglayer mapping
  float dxlo[4], dxhi[4];

  for (int t = 0; t < L_T - 1; ++t){
    if (hg == 0 && w < 4) DECODER(t)   // z_t in bufA; reads drain at bar below

    float dt = times[t+1] - times[t];
    {
      int r = tid >> 5, d = tid & 31;
      const float* cp = coeffs + (b0 + r)*(L_T*DIN) + t*DIN + d;
      dxs[r][d] = (cp[DIN] - cp[0]) / dt;
    }
    bar();
#pragma unroll
    for (int r = 0; r < 4; ++r){
      dxlo[r] = dxs[rt_b*16 + 4*g + r][cl];
      dxhi[r] = dxs[rt_b*16 + 4*g + r][16 + cl];
    }

    for (int s = 0; s < 4; ++s){
      DENSE(bufA, bufB, W0, fb0)
      bar();
      DENSE(bufB, bufA, W1, fb1)
      bar();
      DENSE(bufA, bufB, W2, fb2)
      bar();

      // ---- biglayer from LDS-resident wslice: wave (rt_b, hp) -> h {2hp,2hp+1}
      {
        half8 af[4];
#pragma unroll
        for (int kq = 0; kq < 4; ++kq)
          af[kq] = *(const half8*)(bufB + SWZ(rt_b*16 + cl, kq*32 + 8*g));
#pragma unroll
        for (int hl2 = 0; hl2 < 2; ++hl2){
          const int hl = 2*hp + hl2;
          const _Float16* tpA = wslice + (2*hl)*2048 + lane*8;
          const _Float16* tpB = tpA + 2048;
          f32x4 aA = {0.f,0.f,0.f,0.f}, aB = {0.f,0.f,0.f,0.f};
#pragma unroll
          for (int j = 0; j < 4; ++j)
            aA = __builtin_amdgcn_mfma_f32_16x16x32_f16(af[j], *(const half8*)(tpA + 512*j), aA, 0,0,0);
#pragma unroll
          for (int j = 0; j < 4; ++j)
            aB = __builtin_amdgcn_mfma_f32_16x16x32_f16(af[j], *(const half8*)(tpB + 512*j), aB, 0,0,0);
          float bnA = fbfs[(2*hl)*16 + cl], bnB = fbfs[(2*hl + 1)*16 + cl];
          float p[4];
#pragma unroll
          for (int r = 0; r < 4; ++r)
            p[r] = fast_tanh(aA[r] + bnA)*dxlo[r] + fast_tanh(aB[r] + bnB)*dxhi[r];
#pragma unroll
          for (int m = 1; m < 16; m <<= 1){
#pragma unroll
            for (int r = 0; r < 4; ++r) p[r] += __shfl_xor(p[r], m, 64);
          }
          if (cl == 0){
#pragma unroll
            for (int r = 0; r < 4; ++r) dzs[rt_b*16 + 4*g + r][hl] = p[r];
          }
        }
      }
      bar();

      // ---- dz exchange: per-wave coherent stores+flag adds, all-wave spin.
      float* dbuf = dzg + ((4*t + s) & 1) * (B_TOT*HID);
      const unsigned int epoch = (unsigned int)(4*t + s + 1);
      if (tid < 512){   // waves 0..7 produce
        int br = tid >> 4, hl = tid & 15;
        __hip_atomic_store(&dbuf[(b0 + br)*HID + hg*16 + hl], dzs[br][hl],
                           __ATOMIC_RELAXED, __HIP_MEMORY_SCOPE_AGENT);
        asm volatile("s_waitcnt vmcnt(0)" ::: "memory");  // THIS wave's dz at L2
        if (lane == 0)
          __hip_atomic_fetch_add(flag, 1u, __ATOMIC_RELAXED,
                                 __HIP_MEMORY_SCOPE_AGENT);
      }
      // every wave spins independently (uniform branch; 1 coalesced load/poll)
      while (__hip_atomic_load(flag, __ATOMIC_RELAXED, __HIP_MEMORY_SCOPE_AGENT)
             < 64u * epoch)
        __builtin_amdgcn_s_sleep(1);
      float kv[4];
      {
        const float* src = dbuf + (b0 + cr)*HID + cc;
#pragma unroll
        for (int j = 0; j < 4; ++j)
          kv[j] = __hip_atomic_load(&src[j], __ATOMIC_RELAXED,
                                    __HIP_MEMORY_SCOPE_AGENT);
      }
      // ---- RK4 combine (state in registers, 4 elems/thread)
#pragma unroll
      for (int j = 0; j < 4; ++j){
        float nin;
        if (s == 0){ ka[j] = kv[j];        nin = zf[j] + 0.5f*dt*kv[j]; }
        else if (s == 1){ ka[j] += 2.f*kv[j]; nin = zf[j] + 0.5f*dt*kv[j]; }
        else if (s == 2){ ka[j] += 2.f*kv[j]; nin = zf[j] + dt*kv[j]; }
        else { zf[j] += (dt*(1.f/6.f))*(ka[j] + kv[j]); nin = zf[j]; }
        bufA[SWZ(cr, cc + j)] = (_Float16)nin;
      }
      bar();
    }
  }
  if (hg == 0 && w < 4) DECODER(L_T - 1)
}

extern "C" void kernel_launch(void* const* d_in, const int* in_sizes, int n_in,
                              void* d_out, int out_size, void* d_ws, size_t ws_size,
                              hipStream_t stream){
  const float* coeffs = (const float*)d_in[0];
  const float* times  = (const float*)d_in[1];
  const float* init_w = (const float*)d_in[2];
  const float* init_b = (const float*)d_in[3];
  const float* fw0    = (const float*)d_in[4];
  const float* fb0    = (const float*)d_in[5];
  const float* fw1    = (const float*)d_in[6];
  const float* fb1    = (const float*)d_in[7];
  const float* fw2    = (const float*)d_in[8];
  const float* fb2    = (const float*)d_in[9];
  const float* fwf    = (const float*)d_in[10];
  const float* fbf    = (const float*)d_in[11];
  const float* dec_w  = (const float*)d_in[12];
  const float* dec_b  = (const float*)d_in[13];
  _Float16* W  = (_Float16*)d_ws;
  float* dzg   = (float*)((char*)d_ws + 1163264);        // 2 x 1024x128 f32
  unsigned int* flags = (unsigned int*)((char*)d_ws + 2211840); // 32 x 128B
  float* outf  = (float*)d_out;

  hipLaunchKernelGGL(reorder_w, dim3(64),   dim3(256), 0, stream, fw0, W,          128, 128);
  hipLaunchKernelGGL(reorder_w, dim3(64),   dim3(256), 0, stream, fw1, W + 16384,  128, 128);
  hipLaunchKernelGGL(reorder_w, dim3(64),   dim3(256), 0, stream, fw2, W + 32768,  128, 128);
  hipLaunchKernelGGL(reorder_w, dim3(2048), dim3(256), 0, stream, fwf, W + 49152,  4096, 128);
  hipLaunchKernelGGL(reorder_w, dim3(16),   dim3(256), 0, stream, init_w, W + 573440, 128, 32);
  hipLaunchKernelGGL(reorder_w, dim3(16),   dim3(256), 0, stream, dec_w,  W + 577536,  32, 128);
  hipMemsetAsync(flags, 0, 32 * 128, stream);   // epochs restart every launch

  void* kargs[] = {(void*)&coeffs, (void*)&times, (void*)&init_b, (void*)&fb0,
                   (void*)&fb1, (void*)&fb2, (void*)&fbf, (void*)&dec_b,
                   (void*)&W, (void*)&dzg, (void*)&flags, (void*)&outf};
  hipLaunchCooperativeKernel((const void*)cde_main, dim3(NBLK), dim3(NTHREADS),
                             kargs, 0, stream);
}

// Round 23
// 3487.873 us; speedup vs baseline: 1.5527x; 1.5527x over previous
//
#include <hip/hip_runtime.h>

#define B_TOT 1024
#define L_T   100
#define DIN   32
#define HID   128
#define DOUT  32
#define BT    32      // batch rows per block
#define NHG   8       // h-groups (fwf split 8 ways -> 128 KiB LDS slice)
#define NBLK  256     // 32 batch-tiles x 8 h-groups = 256 CUs, 1 block/CU
#define NTHREADS 1024 // 16 waves

typedef _Float16 half8 __attribute__((ext_vector_type(8)));
typedef float    f32x4 __attribute__((ext_vector_type(4)));

// XOR-swizzled index into a [rows][128] f16 LDS tile (conflict-free b128 reads)
#define SWZ(r,c) (((r) << 7) + ((c) ^ (((r) & 7) << 3)))

__device__ __forceinline__ float fast_exp2(float x){
#if __has_builtin(__builtin_amdgcn_exp2f)
  return __builtin_amdgcn_exp2f(x);
#else
  float r; asm("v_exp_f32 %0, %1\n\ts_nop 1" : "=v"(r) : "v"(x)); return r;
#endif
}
__device__ __forceinline__ float fast_rcp(float x){
#if __has_builtin(__builtin_amdgcn_rcpf)
  return __builtin_amdgcn_rcpf(x);
#else
  float r; asm("v_rcp_f32 %0, %1\n\ts_nop 1" : "=v"(r) : "v"(x)); return r;
#endif
}
__device__ __forceinline__ float fast_tanh(float x){
  float e = fast_exp2(x * 2.885390081777926f);  // 2*log2(e)
  return 1.0f - 2.0f * fast_rcp(e + 1.0f);
}

// Reorder [N][K] f32 row-major weights into fragment-ready f16 tiles:
// dst[((tile*(K/32)+k0)*64 + lane)*8 + ki], lane = (n&15) + 16*((k>>3)&3)
__global__ void reorder_w(const float* __restrict__ src, _Float16* __restrict__ dst,
                          int N, int K){
  int id = blockIdx.x * 256 + threadIdx.x;
  if (id >= N * K) return;
  int n = id / K, k = id - n * K;
  int tile = n >> 4, nl = n & 15;
  int kq = (k >> 3) & 3, k0 = k >> 5, ki = k & 7;
  int lane = nl + (kq << 4);
  int K32 = K >> 5;
  dst[(((tile * K32 + k0) << 6) + lane) * 8 + ki] = (_Float16)src[id];
}

// r21 winner (3037 us) + ONE isolated change: per-wave producer flag adds.
// Each dz-storing wave (0..7) drains its OWN vmcnt(0) then lane-0 adds to
// the group flag (target 64*epoch) -> the pre-flag 16-wave block barrier is
// removed. Consumer side UNCHANGED from r21: tid0-only spin + broadcast
// barrier (r22 proved 16 waves/block spinning on one line serializes the
// L2 atomic path: 3037 -> 5415 us; this keeps 1 spinner/block).
__global__ __launch_bounds__(NTHREADS) void cde_main(
    const float* __restrict__ coeffs, const float* __restrict__ times,
    const float* __restrict__ init_b, const float* __restrict__ fb0,
    const float* __restrict__ fb1,    const float* __restrict__ fb2,
    const float* __restrict__ fbf,    const float* __restrict__ dec_b,
    const _Float16* __restrict__ W,   float* __restrict__ dzg,
    unsigned int* __restrict__ flags, float* __restrict__ out)
{
  __shared__ _Float16 wslice[32*2048]; // 128 KiB: this block's fwf tiles (resident)
  __shared__ _Float16 bufA[BT*HID];    // 8 KiB ping-pong activations (f16, swizzled)
  __shared__ _Float16 bufB[BT*HID];    // 8 KiB
  __shared__ float    dzs[BT][16];     // 2 KiB  dz slice staging
  __shared__ float    dxs[BT][DIN];    // 4 KiB  dX/dt
  __shared__ float    fbfs[512];       // 2 KiB  fbf slice
  // total 155,648 B < 160 KiB

  const int tid  = threadIdx.x;
  const int lane = tid & 63;
  const int w    = tid >> 6;   // wave 0..15
  const int cl   = lane & 15;
  const int g    = lane >> 4;
  const int hg   = blockIdx.x >> 5;  // h-group (XCD-local grouping)
  const int bt   = blockIdx.x & 31;  // batch tile; group = {bt+32*hg} all same XCD
  const int b0   = bt * BT;
  const int cr   = tid >> 5;         // combine row 0..31
  const int cc   = (tid & 31) * 4;   // combine col base

  const _Float16* W0 = W;
  const _Float16* W1 = W + 16384;
  const _Float16* W2 = W + 32768;
  const _Float16* Wf = W + 49152;   // fwf: 256 tiles
  const _Float16* Wi = W + 573440;  // init_w
  const _Float16* Wd = W + 577536;  // dec_w
  const _Float16* Wfs = Wf + hg * 32 * 2048;  // this block's 32 tiles
  unsigned int* flag = flags + bt * 32;       // 128B-strided counter per group

  // lgkm-only local barrier (two-sided clobbers + sched pins).
  auto bar = [&]{
    __builtin_amdgcn_sched_barrier(0);
    asm volatile("s_waitcnt lgkmcnt(0)" ::: "memory");
    __builtin_amdgcn_s_barrier();
    __builtin_amdgcn_sched_barrier(0);
    asm volatile("" ::: "memory");
  };

  // fbf slice (global idx = 512*hg + t_local*16 + nl)
  if (tid < 512) fbfs[tid] = fbf[hg*512 + tid];

  // ---- init: z0 = coeffs[:,0,:] @ init_w.T + init_b (wslice as f32 scratch)
  float* scratch = (float*)wslice;   // [32][128] f32, overwritten later
  {
    int r = tid >> 5, d = tid & 31;
    bufB[SWZ(r, d)] = (_Float16)coeffs[(b0 + r)*(L_T*DIN) + d];
  }
  bar();
  {
    const int rt = w >> 3, ct = w & 7;
    f32x4 acc = {0.f,0.f,0.f,0.f};
    half8 a = *(const half8*)(bufB + SWZ(rt*16 + cl, 8*g));
    half8 b = *(const half8*)(Wi + (ct*64 + lane)*8);
    acc = __builtin_amdgcn_mfma_f32_16x16x32_f16(a, b, acc, 0, 0, 0);
    float bn = init_b[ct*16 + cl];
#pragma unroll
    for (int r = 0; r < 4; ++r){
      float v = acc[r] + bn;
      scratch[(rt*16 + 4*g + r)*128 + ct*16 + cl] = v;
      bufA[SWZ(rt*16 + 4*g + r, ct*16 + cl)] = (_Float16)v;
    }
  }
  bar();
  float zf[4], ka[4] = {0.f,0.f,0.f,0.f};
#pragma unroll
  for (int j = 0; j < 4; ++j) zf[j] = scratch[cr*128 + cc + j];
  bar();
  // ---- fwf slice -> LDS (once; replaces scratch)
  for (int i = tid*8; i < 32*2048; i += NTHREADS*8)
    *(half8*)(wslice + i) = *(const half8*)(Wfs + i);
  bar();

// Dense HID->HID, all 16 waves (rt=w>>3, ct=w&7), weights from L2/L3.
#define DENSE(IN, OB, WT, BIAS) {                                          \
    const int rt = w >> 3, ct = w & 7;                                     \
    f32x4 acc = {0.f,0.f,0.f,0.f};                                         \
    _Pragma("unroll")                                                      \
    for (int kq = 0; kq < 4; ++kq){                                        \
      half8 a = *(const half8*)((IN) + SWZ(rt*16 + cl, kq*32 + 8*g));      \
      half8 b = *(const half8*)((WT) + ((ct*4 + kq)*64 + lane)*8);         \
      acc = __builtin_amdgcn_mfma_f32_16x16x32_f16(a, b, acc, 0,0,0);}     \
    float bn = (BIAS)[ct*16 + cl];                                         \
    _Pragma("unroll")                                                      \
    for (int r = 0; r < 4; ++r)                                            \
      (OB)[SWZ(rt*16 + 4*g + r, ct*16 + cl)] = (_Float16)fast_tanh(acc[r] + bn); }

// Decoder (hg==0 blocks, waves 0..3): rt=w>>1, ct=w&1
#define DECODER(TS) {                                                      \
    const int rt = w >> 1, ct = w & 1;                                     \
    f32x4 acc = {0.f,0.f,0.f,0.f};                                         \
    _Pragma("unroll")                                                      \
    for (int kq = 0; kq < 4; ++kq){                                        \
      half8 a = *(const half8*)(bufA + SWZ(rt*16 + cl, kq*32 + 8*g));      \
      half8 b = *(const half8*)(Wd + ((ct*4 + kq)*64 + lane)*8);           \
      acc = __builtin_amdgcn_mfma_f32_16x16x32_f16(a, b, acc, 0,0,0);}     \
    float bn = dec_b[ct*16 + cl];                                          \
    _Pragma("unroll")                                                      \
    for (int r = 0; r < 4; ++r)                                            \
      out[(b0 + rt*16 + 4*g + r)*(L_T*DOUT) + (TS)*DOUT + ct*16 + cl] = acc[r] + bn; }

  const int rt_b = w & 1, hp = w >> 1;   // biglayer mapping
  float dxlo[4], dxhi[4];

  for (int t = 0; t < L_T - 1; ++t){
    if (hg == 0 && w < 4) DECODER(t)   // z_t in bufA; reads drain at bar below

    float dt = times[t+1] - times[t];
    {
      int r = tid >> 5, d = tid & 31;
      const float* cp = coeffs + (b0 + r)*(L_T*DIN) + t*DIN + d;
      dxs[r][d] = (cp[DIN] - cp[0]) / dt;
    }
    bar();
#pragma unroll
    for (int r = 0; r < 4; ++r){
      dxlo[r] = dxs[rt_b*16 + 4*g + r][cl];
      dxhi[r] = dxs[rt_b*16 + 4*g + r][16 + cl];
    }

    for (int s = 0; s < 4; ++s){
      DENSE(bufA, bufB, W0, fb0)
      bar();
      DENSE(bufB, bufA, W1, fb1)
      bar();
      DENSE(bufA, bufB, W2, fb2)
      bar();

      // ---- biglayer from LDS-resident wslice: wave (rt_b, hp) -> h {2hp,2hp+1}
      {
        half8 af[4];
#pragma unroll
        for (int kq = 0; kq < 4; ++kq)
          af[kq] = *(const half8*)(bufB + SWZ(rt_b*16 + cl, kq*32 + 8*g));
#pragma unroll
        for (int hl2 = 0; hl2 < 2; ++hl2){
          const int hl = 2*hp + hl2;
          const _Float16* tpA = wslice + (2*hl)*2048 + lane*8;
          const _Float16* tpB = tpA + 2048;
          f32x4 aA = {0.f,0.f,0.f,0.f}, aB = {0.f,0.f,0.f,0.f};
#pragma unroll
          for (int j = 0; j < 4; ++j)
            aA = __builtin_amdgcn_mfma_f32_16x16x32_f16(af[j], *(const half8*)(tpA + 512*j), aA, 0,0,0);
#pragma unroll
          for (int j = 0; j < 4; ++j)
            aB = __builtin_amdgcn_mfma_f32_16x16x32_f16(af[j], *(const half8*)(tpB + 512*j), aB, 0,0,0);
          float bnA = fbfs[(2*hl)*16 + cl], bnB = fbfs[(2*hl + 1)*16 + cl];
          float p[4];
#pragma unroll
          for (int r = 0; r < 4; ++r)
            p[r] = fast_tanh(aA[r] + bnA)*dxlo[r] + fast_tanh(aB[r] + bnB)*dxhi[r];
#pragma unroll
          for (int m = 1; m < 16; m <<= 1){
#pragma unroll
            for (int r = 0; r < 4; ++r) p[r] += __shfl_xor(p[r], m, 64);
          }
          if (cl == 0){
#pragma unroll
            for (int r = 0; r < 4; ++r) dzs[rt_b*16 + 4*g + r][hl] = p[r];
          }
        }
      }
      bar();

      // ---- dz exchange: per-wave coherent stores + flag adds (no pre-flag
      // barrier); tid0-only spin + broadcast barrier (r21 consumer side).
      float* dbuf = dzg + ((4*t + s) & 1) * (B_TOT*HID);
      const unsigned int epoch = (unsigned int)(4*t + s + 1);
      if (tid < 512){   // waves 0..7 produce
        int br = tid >> 4, hl = tid & 15;
        __hip_atomic_store(&dbuf[(b0 + br)*HID + hg*16 + hl], dzs[br][hl],
                           __ATOMIC_RELAXED, __HIP_MEMORY_SCOPE_AGENT);
        asm volatile("s_waitcnt vmcnt(0)" ::: "memory");  // THIS wave's dz at L2
        if (lane == 0)
          __hip_atomic_fetch_add(flag, 1u, __ATOMIC_RELAXED,
                                 __HIP_MEMORY_SCOPE_AGENT);
      }
      if (tid == 0){
        while (__hip_atomic_load(flag, __ATOMIC_RELAXED, __HIP_MEMORY_SCOPE_AGENT)
               < 64u * epoch)
          __builtin_amdgcn_s_sleep(2);
      }
      bar();                                            // broadcast readiness
      float kv[4];
      {
        const float* src = dbuf + (b0 + cr)*HID + cc;
#pragma unroll
        for (int j = 0; j < 4; ++j)
          kv[j] = __hip_atomic_load(&src[j], __ATOMIC_RELAXED,
                                    __HIP_MEMORY_SCOPE_AGENT);
      }
      // ---- RK4 combine (state in registers, 4 elems/thread)
#pragma unroll
      for (int j = 0; j < 4; ++j){
        float nin;
        if (s == 0){ ka[j] = kv[j];        nin = zf[j] + 0.5f*dt*kv[j]; }
        else if (s == 1){ ka[j] += 2.f*kv[j]; nin = zf[j] + 0.5f*dt*kv[j]; }
        else if (s == 2){ ka[j] += 2.f*kv[j]; nin = zf[j] + dt*kv[j]; }
        else { zf[j] += (dt*(1.f/6.f))*(ka[j] + kv[j]); nin = zf[j]; }
        bufA[SWZ(cr, cc + j)] = (_Float16)nin;
      }
      bar();
    }
  }
  if (hg == 0 && w < 4) DECODER(L_T - 1)
}

extern "C" void kernel_launch(void* const* d_in, const int* in_sizes, int n_in,
                              void* d_out, int out_size, void* d_ws, size_t ws_size,
                              hipStream_t stream){
  const float* coeffs = (const float*)d_in[0];
  const float* times  = (const float*)d_in[1];
  const float* init_w = (const float*)d_in[2];
  const float* init_b = (const float*)d_in[3];
  const float* fw0    = (const float*)d_in[4];
  const float* fb0    = (const float*)d_in[5];
  const float* fw1    = (const float*)d_in[6];
  const float* fb1    = (const float*)d_in[7];
  const float* fw2    = (const float*)d_in[8];
  const float* fb2    = (const float*)d_in[9];
  const float* fwf    = (const float*)d_in[10];
  const float* fbf    = (const float*)d_in[11];
  const float* dec_w  = (const float*)d_in[12];
  const float* dec_b  = (const float*)d_in[13];
  _Float16* W  = (_Float16*)d_ws;
  float* dzg   = (float*)((char*)d_ws + 1163264);        // 2 x 1024x128 f32
  unsigned int* flags = (unsigned int*)((char*)d_ws + 2211840); // 32 x 128B
  float* outf  = (float*)d_out;

  hipLaunchKernelGGL(reorder_w, dim3(64),   dim3(256), 0, stream, fw0, W,          128, 128);
  hipLaunchKernelGGL(reorder_w, dim3(64),   dim3(256), 0, stream, fw1, W + 16384,  128, 128);
  hipLaunchKernelGGL(reorder_w, dim3(64),   dim3(256), 0, stream, fw2, W + 32768,  128, 128);
  hipLaunchKernelGGL(reorder_w, dim3(2048), dim3(256), 0, stream, fwf, W + 49152,  4096, 128);
  hipLaunchKernelGGL(reorder_w, dim3(16),   dim3(256), 0, stream, init_w, W + 573440, 128, 32);
  hipLaunchKernelGGL(reorder_w, dim3(16),   dim3(256), 0, stream, dec_w,  W + 577536,  32, 128);
  hipMemsetAsync(flags, 0, 32 * 128, stream);   // epochs restart every launch

  void* kargs[] = {(void*)&coeffs, (void*)&times, (void*)&init_b, (void*)&fb0,
                   (void*)&fb1, (void*)&fb2, (void*)&fbf, (void*)&dec_b,
                   (void*)&W, (void*)&dzg, (void*)&flags, (void*)&outf};
  hipLaunchCooperativeKernel((const void*)cde_main, dim3(NBLK), dim3(NTHREADS),
                             kargs, 0, stream);
}

// Round 24
// 3023.049 us; speedup vs baseline: 1.7914x; 1.1538x over previous
//
#include <hip/hip_runtime.h>

#define B_TOT 1024
#define L_T   100
#define DIN   32
#define HID   128
#define DOUT  32
#define BT    32      // batch rows per block
#define NHG   8       // h-groups (fwf split 8 ways -> 128 KiB LDS slice)
#define NBLK  256     // 32 batch-tiles x 8 h-groups = 256 CUs, 1 block/CU
#define NTHREADS 1024 // 16 waves

typedef _Float16 half8 __attribute__((ext_vector_type(8)));
typedef float    f32x4 __attribute__((ext_vector_type(4)));

// XOR-swizzled index into a [rows][128] f16 LDS tile (conflict-free b128 reads)
#define SWZ(r,c) (((r) << 7) + ((c) ^ (((r) & 7) << 3)))

__device__ __forceinline__ float fast_exp2(float x){
#if __has_builtin(__builtin_amdgcn_exp2f)
  return __builtin_amdgcn_exp2f(x);
#else
  float r; asm("v_exp_f32 %0, %1\n\ts_nop 1" : "=v"(r) : "v"(x)); return r;
#endif
}
__device__ __forceinline__ float fast_rcp(float x){
#if __has_builtin(__builtin_amdgcn_rcpf)
  return __builtin_amdgcn_rcpf(x);
#else
  float r; asm("v_rcp_f32 %0, %1\n\ts_nop 1" : "=v"(r) : "v"(x)); return r;
#endif
}
__device__ __forceinline__ float fast_tanh(float x){
  float e = fast_exp2(x * 2.885390081777926f);  // 2*log2(e)
  return 1.0f - 2.0f * fast_rcp(e + 1.0f);
}

// Reorder [N][K] f32 row-major weights into fragment-ready f16 tiles:
// dst[((tile*(K/32)+k0)*64 + lane)*8 + ki], lane = (n&15) + 16*((k>>3)&3)
__global__ void reorder_w(const float* __restrict__ src, _Float16* __restrict__ dst,
                          int N, int K){
  int id = blockIdx.x * 256 + threadIdx.x;
  if (id >= N * K) return;
  int n = id / K, k = id - n * K;
  int tile = n >> 4, nl = n & 15;
  int kq = (k >> 3) & 3, k0 = k >> 5, ki = k & 7;
  int lane = nl + (kq << 4);
  int K32 = K >> 5;
  dst[(((tile * K32 + k0) << 6) + lane) * 8 + ki] = (_Float16)src[id];
}

// FINAL (r21 configuration, best measured: 3037 us, 2.03x vs baseline).
// h-split structure: fwf LDS-resident per block (zero per-stage weight
// re-streaming), per-batch-group flag sync with XCD-LOCAL groups
// (hg=blockIdx>>5, bt=blockIdx&31: all 8 group members on one XCD; dz +
// flag lines stay in the local L2 — FETCH dropped 885->119 MB vs the
// cross-XCD mapping). Exchange is fence-free: device-scope coherent
// stores/loads move dz through the coherence point; no L2 inv/wbl2.
// Exchange variants all tested and worse: threadfence (r16 +4.9ms),
// f16x2 packing (r18 +0.4ms, partial-line RMW), all-wave spin (r22
// +2.4ms, atomic serialization), per-wave flag adds (r23 +0.45ms).
// Remaining ceiling is structural: 396 sequential {MLP latency chain +
// cross-CU reduce} rendezvous; no HW resource saturated (HBM 1.5%,
// MFMA 10%, VALU 32%); 64-VGPR cap for 1024-thread blocks forbids any
// register-costing optimization (r19: +2 regs -> spill).
__global__ __launch_bounds__(NTHREADS) void cde_main(
    const float* __restrict__ coeffs, const float* __restrict__ times,
    const float* __restrict__ init_b, const float* __restrict__ fb0,
    const float* __restrict__ fb1,    const float* __restrict__ fb2,
    const float* __restrict__ fbf,    const float* __restrict__ dec_b,
    const _Float16* __restrict__ W,   float* __restrict__ dzg,
    unsigned int* __restrict__ flags, float* __restrict__ out)
{
  __shared__ _Float16 wslice[32*2048]; // 128 KiB: this block's fwf tiles (resident)
  __shared__ _Float16 bufA[BT*HID];    // 8 KiB ping-pong activations (f16, swizzled)
  __shared__ _Float16 bufB[BT*HID];    // 8 KiB
  __shared__ float    dzs[BT][16];     // 2 KiB  dz slice staging
  __shared__ float    dxs[BT][DIN];    // 4 KiB  dX/dt
  __shared__ float    fbfs[512];       // 2 KiB  fbf slice
  // total 155,648 B < 160 KiB

  const int tid  = threadIdx.x;
  const int lane = tid & 63;
  const int w    = tid >> 6;   // wave 0..15
  const int cl   = lane & 15;
  const int g    = lane >> 4;
  const int hg   = blockIdx.x >> 5;  // h-group (XCD-local grouping)
  const int bt   = blockIdx.x & 31;  // batch tile; group = {bt+32*hg} all same XCD
  const int b0   = bt * BT;
  const int cr   = tid >> 5;         // combine row 0..31
  const int cc   = (tid & 31) * 4;   // combine col base

  const _Float16* W0 = W;
  const _Float16* W1 = W + 16384;
  const _Float16* W2 = W + 32768;
  const _Float16* Wf = W + 49152;   // fwf: 256 tiles
  const _Float16* Wi = W + 573440;  // init_w
  const _Float16* Wd = W + 577536;  // dec_w
  const _Float16* Wfs = Wf + hg * 32 * 2048;  // this block's 32 tiles
  unsigned int* flag = flags + bt * 32;       // 128B-strided counter per group

  // lgkm-only local barrier (two-sided clobbers + sched pins).
  auto bar = [&]{
    __builtin_amdgcn_sched_barrier(0);
    asm volatile("s_waitcnt lgkmcnt(0)" ::: "memory");
    __builtin_amdgcn_s_barrier();
    __builtin_amdgcn_sched_barrier(0);
    asm volatile("" ::: "memory");
  };

  // fbf slice (global idx = 512*hg + t_local*16 + nl)
  if (tid < 512) fbfs[tid] = fbf[hg*512 + tid];

  // ---- init: z0 = coeffs[:,0,:] @ init_w.T + init_b (wslice as f32 scratch)
  float* scratch = (float*)wslice;   // [32][128] f32, overwritten later
  {
    int r = tid >> 5, d = tid & 31;
    bufB[SWZ(r, d)] = (_Float16)coeffs[(b0 + r)*(L_T*DIN) + d];
  }
  bar();
  {
    const int rt = w >> 3, ct = w & 7;
    f32x4 acc = {0.f,0.f,0.f,0.f};
    half8 a = *(const half8*)(bufB + SWZ(rt*16 + cl, 8*g));
    half8 b = *(const half8*)(Wi + (ct*64 + lane)*8);
    acc = __builtin_amdgcn_mfma_f32_16x16x32_f16(a, b, acc, 0, 0, 0);
    float bn = init_b[ct*16 + cl];
#pragma unroll
    for (int r = 0; r < 4; ++r){
      float v = acc[r] + bn;
      scratch[(rt*16 + 4*g + r)*128 + ct*16 + cl] = v;
      bufA[SWZ(rt*16 + 4*g + r, ct*16 + cl)] = (_Float16)v;
    }
  }
  bar();
  float zf[4], ka[4] = {0.f,0.f,0.f,0.f};
#pragma unroll
  for (int j = 0; j < 4; ++j) zf[j] = scratch[cr*128 + cc + j];
  bar();
  // ---- fwf slice -> LDS (once; replaces scratch)
  for (int i = tid*8; i < 32*2048; i += NTHREADS*8)
    *(half8*)(wslice + i) = *(const half8*)(Wfs + i);
  bar();

// Dense HID->HID, all 16 waves (rt=w>>3, ct=w&7), weights from L2/L3.
#define DENSE(IN, OB, WT, BIAS) {                                          \
    const int rt = w >> 3, ct = w & 7;                                     \
    f32x4 acc = {0.f,0.f,0.f,0.f};                                         \
    _Pragma("unroll")                                                      \
    for (int kq = 0; kq < 4; ++kq){                                        \
      half8 a = *(const half8*)((IN) + SWZ(rt*16 + cl, kq*32 + 8*g));      \
      half8 b = *(const half8*)((WT) + ((ct*4 + kq)*64 + lane)*8);         \
      acc = __builtin_amdgcn_mfma_f32_16x16x32_f16(a, b, acc, 0,0,0);}     \
    float bn = (BIAS)[ct*16 + cl];                                         \
    _Pragma("unroll")                                                      \
    for (int r = 0; r < 4; ++r)                                            \
      (OB)[SWZ(rt*16 + 4*g + r, ct*16 + cl)] = (_Float16)fast_tanh(acc[r] + bn); }

// Decoder (hg==0 blocks, waves 0..3): rt=w>>1, ct=w&1
#define DECODER(TS) {                                                      \
    const int rt = w >> 1, ct = w & 1;                                     \
    f32x4 acc = {0.f,0.f,0.f,0.f};                                         \
    _Pragma("unroll")                                                      \
    for (int kq = 0; kq < 4; ++kq){                                        \
      half8 a = *(const half8*)(bufA + SWZ(rt*16 + cl, kq*32 + 8*g));      \
      half8 b = *(const half8*)(Wd + ((ct*4 + kq)*64 + lane)*8);           \
      acc = __builtin_amdgcn_mfma_f32_16x16x32_f16(a, b, acc, 0,0,0);}     \
    float bn = dec_b[ct*16 + cl];                                          \
    _Pragma("unroll")                                                      \
    for (int r = 0; r < 4; ++r)                                            \
      out[(b0 + rt*16 + 4*g + r)*(L_T*DOUT) + (TS)*DOUT + ct*16 + cl] = acc[r] + bn; }

  const int rt_b = w & 1, hp = w >> 1;   // biglayer mapping
  float dxlo[4], dxhi[4];

  for (int t = 0; t < L_T - 1; ++t){
    if (hg == 0 && w < 4) DECODER(t)   // z_t in bufA; reads drain at bar below

    float dt = times[t+1] - times[t];
    {
      int r = tid >> 5, d = tid & 31;
      const float* cp = coeffs + (b0 + r)*(L_T*DIN) + t*DIN + d;
      dxs[r][d] = (cp[DIN] - cp[0]) / dt;
    }
    bar();
#pragma unroll
    for (int r = 0; r < 4; ++r){
      dxlo[r] = dxs[rt_b*16 + 4*g + r][cl];
      dxhi[r] = dxs[rt_b*16 + 4*g + r][16 + cl];
    }

    for (int s = 0; s < 4; ++s){
      DENSE(bufA, bufB, W0, fb0)
      bar();
      DENSE(bufB, bufA, W1, fb1)
      bar();
      DENSE(bufA, bufB, W2, fb2)
      bar();

      // ---- biglayer from LDS-resident wslice: wave (rt_b, hp) -> h {2hp,2hp+1}
      {
        half8 af[4];
#pragma unroll
        for (int kq = 0; kq < 4; ++kq)
          af[kq] = *(const half8*)(bufB + SWZ(rt_b*16 + cl, kq*32 + 8*g));
#pragma unroll
        for (int hl2 = 0; hl2 < 2; ++hl2){
          const int hl = 2*hp + hl2;
          const _Float16* tpA = wslice + (2*hl)*2048 + lane*8;
          const _Float16* tpB = tpA + 2048;
          f32x4 aA = {0.f,0.f,0.f,0.f}, aB = {0.f,0.f,0.f,0.f};
#pragma unroll
          for (int j = 0; j < 4; ++j)
            aA = __builtin_amdgcn_mfma_f32_16x16x32_f16(af[j], *(const half8*)(tpA + 512*j), aA, 0,0,0);
#pragma unroll
          for (int j = 0; j < 4; ++j)
            aB = __builtin_amdgcn_mfma_f32_16x16x32_f16(af[j], *(const half8*)(tpB + 512*j), aB, 0,0,0);
          float bnA = fbfs[(2*hl)*16 + cl], bnB = fbfs[(2*hl + 1)*16 + cl];
          float p[4];
#pragma unroll
          for (int r = 0; r < 4; ++r)
            p[r] = fast_tanh(aA[r] + bnA)*dxlo[r] + fast_tanh(aB[r] + bnB)*dxhi[r];
#pragma unroll
          for (int m = 1; m < 16; m <<= 1){
#pragma unroll
            for (int r = 0; r < 4; ++r) p[r] += __shfl_xor(p[r], m, 64);
          }
          if (cl == 0){
#pragma unroll
            for (int r = 0; r < 4; ++r) dzs[rt_b*16 + 4*g + r][hl] = p[r];
          }
        }
      }
      bar();

      // ---- dz exchange: coherent stores -> flag -> coherent loads (NO fences)
      float* dbuf = dzg + ((4*t + s) & 1) * (B_TOT*HID);
      if (tid < 512){
        int br = tid >> 4, hl = tid & 15;
        __hip_atomic_store(&dbuf[(b0 + br)*HID + hg*16 + hl], dzs[br][hl],
                           __ATOMIC_RELAXED, __HIP_MEMORY_SCOPE_AGENT);
      }
      asm volatile("s_waitcnt vmcnt(0)" ::: "memory");  // dz at coherence point
      bar();                                            // all waves' stores done
      const unsigned int epoch = (unsigned int)(4*t + s + 1);
      if (tid == 0){
        __hip_atomic_fetch_add(flag, 1u, __ATOMIC_RELAXED, __HIP_MEMORY_SCOPE_AGENT);
        while (__hip_atomic_load(flag, __ATOMIC_RELAXED, __HIP_MEMORY_SCOPE_AGENT)
               < 8u * epoch)
          __builtin_amdgcn_s_sleep(2);
      }
      bar();                                            // broadcast readiness
      float kv[4];
      {
        const float* src = dbuf + (b0 + cr)*HID + cc;
#pragma unroll
        for (int j = 0; j < 4; ++j)
          kv[j] = __hip_atomic_load(&src[j], __ATOMIC_RELAXED,
                                    __HIP_MEMORY_SCOPE_AGENT);
      }
      // ---- RK4 combine (state in registers, 4 elems/thread)
#pragma unroll
      for (int j = 0; j < 4; ++j){
        float nin;
        if (s == 0){ ka[j] = kv[j];        nin = zf[j] + 0.5f*dt*kv[j]; }
        else if (s == 1){ ka[j] += 2.f*kv[j]; nin = zf[j] + 0.5f*dt*kv[j]; }
        else if (s == 2){ ka[j] += 2.f*kv[j]; nin = zf[j] + dt*kv[j]; }
        else { zf[j] += (dt*(1.f/6.f))*(ka[j] + kv[j]); nin = zf[j]; }
        bufA[SWZ(cr, cc + j)] = (_Float16)nin;
      }
      bar();
    }
  }
  if (hg == 0 && w < 4) DECODER(L_T - 1)
}

extern "C" void kernel_launch(void* const* d_in, const int* in_sizes, int n_in,
                              void* d_out, int out_size, void* d_ws, size_t ws_size,
                              hipStream_t stream){
  const float* coeffs = (const float*)d_in[0];
  const float* times  = (const float*)d_in[1];
  const float* init_w = (const float*)d_in[2];
  const float* init_b = (const float*)d_in[3];
  const float* fw0    = (const float*)d_in[4];
  const float* fb0    = (const float*)d_in[5];
  const float* fw1    = (const float*)d_in[6];
  const float* fb1    = (const float*)d_in[7];
  const float* fw2    = (const float*)d_in[8];
  const float* fb2    = (const float*)d_in[9];
  const float* fwf    = (const float*)d_in[10];
  const float* fbf    = (const float*)d_in[11];
  const float* dec_w  = (const float*)d_in[12];
  const float* dec_b  = (const float*)d_in[13];
  _Float16* W  = (_Float16*)d_ws;
  float* dzg   = (float*)((char*)d_ws + 1163264);        // 2 x 1024x128 f32
  unsigned int* flags = (unsigned int*)((char*)d_ws + 2211840); // 32 x 128B
  float* outf  = (float*)d_out;

  hipLaunchKernelGGL(reorder_w, dim3(64),   dim3(256), 0, stream, fw0, W,          128, 128);
  hipLaunchKernelGGL(reorder_w, dim3(64),   dim3(256), 0, stream, fw1, W + 16384,  128, 128);
  hipLaunchKernelGGL(reorder_w, dim3(64),   dim3(256), 0, stream, fw2, W + 32768,  128, 128);
  hipLaunchKernelGGL(reorder_w, dim3(2048), dim3(256), 0, stream, fwf, W + 49152,  4096, 128);
  hipLaunchKernelGGL(reorder_w, dim3(16),   dim3(256), 0, stream, init_w, W + 573440, 128, 32);
  hipLaunchKernelGGL(reorder_w, dim3(16),   dim3(256), 0, stream, dec_w,  W + 577536,  32, 128);
  hipMemsetAsync(flags, 0, 32 * 128, stream);   // epochs restart every launch

  void* kargs[] = {(void*)&coeffs, (void*)&times, (void*)&init_b, (void*)&fb0,
                   (void*)&fb1, (void*)&fb2, (void*)&fbf, (void*)&dec_b,
                   (void*)&W, (void*)&dzg, (void*)&flags, (void*)&outf};
  hipLaunchCooperativeKernel((const void*)cde_main, dim3(NBLK), dim3(NTHREADS),
                             kargs, 0, stream);
}